// Round 10
// baseline (286.450 us; speedup 1.0000x reference)
//
#include <hip/hip_runtime.h>
#include <hip/hip_bf16.h>
#include <stdint.h>

typedef __attribute__((ext_vector_type(8))) short bf16x8;
typedef __attribute__((ext_vector_type(4))) float f32x4v;
typedef __attribute__((ext_vector_type(16))) float f32x16;

#define CH_STRIDE 65536       // x: T*W*H floats per channel
#define SLICE_STRIDE 540672   // xT bytes per (b,t) slice = 64*4*66*2*16
#define ROW_STRIDE 8448       // xT bytes per w row = 4*66*2*16
#define S_STRIDE 2112         // xT bytes per oct-pair = 66*2*16

__device__ __forceinline__ uint16_t f2bf(float f) {
  uint32_t u = __builtin_bit_cast(uint32_t, f);
  u = (u + 0x7FFFu + ((u >> 16) & 1u)) >> 16;
  return (uint16_t)u;
}
__device__ __forceinline__ float bf2f(uint32_t b) {
  return __builtin_bit_cast(float, b << 16);
}
__device__ __forceinline__ uint16_t cvt_bf(float f) {
  return __builtin_bit_cast(uint16_t, __float2bfloat16(f));
}

#define MFMA32(a, b, c) __builtin_amdgcn_mfma_f32_32x32x16_bf16(a, b, c, 0, 0, 0)

// ---------------------------------------------------------------------------
// prep: fp32 [o][i][tap] -> bf16 tables. [0..36863] q: [tap][oct][row][j];
// [36864..] kv: [tap][oct][rowloc][j] (rowloc<64 = k rows, else v rows).
// ---------------------------------------------------------------------------
__global__ void prep_weights(const float* __restrict__ wq, const float* __restrict__ wk,
                             const float* __restrict__ wv, uint16_t* __restrict__ wout) {
  int i = blockIdx.x * 256 + threadIdx.x;
  if (i >= 110592) return;
  if (i < 36864) {
    int tap = i >> 12, oct = (i >> 9) & 7, row = (i >> 3) & 63, j = i & 7;
    wout[i] = f2bf(wq[(row * 64 + oct * 8 + j) * 9 + tap]);
  } else {
    int m = i - 36864;
    int tap = m >> 13, oct = (m >> 10) & 7, rl = (m >> 3) & 127, j = m & 7;
    const float* src = (rl < 64) ? wk : wv;
    wout[i] = f2bf(src[((rl & 63) * 64 + oct * 8 + j) * 9 + tap]);
  }
}

// ---------------------------------------------------------------------------
// transpose_x: x fp32 [b][c][t][w][h] -> xT bf16 [slice][w][s4][h'66][lh2][8ch]
// h' = h+1, zeros at h'=0,65. One block = (slice, 4 w-rows).
// ---------------------------------------------------------------------------
__global__ __launch_bounds__(256, 4) void transpose_x(const float* __restrict__ x,
                                                      uint8_t* __restrict__ xT) {
  __shared__ uint8_t lds[4 * 8 * 66 * 16];  // [r4][oct8][col66] 16B frags
  const int tid = threadIdx.x;
  const int bid = blockIdx.x;
  const int rg = bid & 15, slice = bid >> 4;
  const int b = slice >> 4, t = slice & 15;
  const int w0 = rg * 4;
  const float* xs = x + ((size_t)b * 1024 + t) * 4096;

  if (tid < 64) {  // h halo: col 0 and 65 = zeros
    int r = tid >> 4, rem = tid & 15;
    int oct = rem >> 1, side = rem & 1;
    bf16x8 z = {};
    *(bf16x8*)(lds + (uint32_t)((r * 8 + oct) * 66 + side * 65) * 16u) = z;
  }
  #pragma unroll
  for (int k = 0; k < 2; ++k) {
    int u = tid + k * 256;               // 512 units: r4 x oct8 x g16
    int r = u >> 7, oct = (u >> 4) & 7, g = u & 15;
    const float* p = xs + (size_t)(oct * 8) * CH_STRIDE + (w0 + r) * 64 + 4 * g;
    f32x4v v[8];
    #pragma unroll
    for (int j = 0; j < 8; ++j) v[j] = *(const f32x4v*)(p + (size_t)j * CH_STRIDE);
    uint32_t base = (uint32_t)((r * 8 + oct) * 66 + 4 * g + 1) * 16u;
    #pragma unroll
    for (int c = 0; c < 4; ++c) {
      bf16x8 frag;
      #pragma unroll
      for (int q = 0; q < 8; ++q) frag[q] = (short)cvt_bf(v[q][c]);
      *(bf16x8*)(lds + base + (uint32_t)c * 16u) = frag;
    }
  }
  __syncthreads();

  uint8_t* dst = xT + (size_t)slice * SLICE_STRIDE + (size_t)w0 * ROW_STRIDE;
  for (int i = tid; i < 2112; i += 256) {  // r4 x (s4 x h66 x lh2 = 528)
    int r = i / 528;
    int j = i - r * 528;                   // j = s*132 + h'*2 + lh
    int s = j / 132;
    int j2 = j - s * 132;
    int hp = j2 >> 1, lh = j2 & 1;
    int oct = s * 2 + lh;
    bf16x8 frag = *(const bf16x8*)(lds + (uint32_t)((r * 8 + oct) * 66 + hp) * 16u);
    *(bf16x8*)(dst + (size_t)r * ROW_STRIDE + (uint32_t)j * 16u) = frag;
  }
}

// ---------------------------------------------------------------------------
// KV: zero LDS, zero barriers. 4 waves/block, wave = output row ng.
// All operands from global (weights L1/L2-hot, xT L2/L3-hot, coalesced 1KB).
// ---------------------------------------------------------------------------
__global__ __launch_bounds__(256, 2) void kv_s_kernel(
    const uint8_t* __restrict__ xT, const uint16_t* __restrict__ wkv,
    const float* __restrict__ bk, const float* __restrict__ bv,
    float* __restrict__ s_out) {
  const int tid = threadIdx.x;
  const int l = tid & 63, ng = tid >> 6;
  int bid = (int)(blockIdx.x & 7) * 256 + (int)(blockIdx.x >> 3);  // XCD swizzle
  const int rg = bid & 15, slice = bid >> 4;
  const int b = slice >> 4, t = slice & 15;
  const int w0 = rg * 4;
  const int lm = l & 31, lh = l >> 5;
  const uint8_t* xsl = xT + (size_t)slice * SLICE_STRIDE;

  f32x16 accK[2][2], accV[2][2];
  #pragma unroll
  for (int mt = 0; mt < 2; ++mt)
    #pragma unroll
    for (int nt = 0; nt < 2; ++nt)
      #pragma unroll
      for (int q = 0; q < 16; ++q) { accK[mt][nt][q] = 0.f; accV[mt][nt][q] = 0.f; }

  #pragma unroll
  for (int tap = 0; tap < 9; ++tap) {
    const int dy = tap / 3, dx = tap % 3;
    const int w2 = w0 + ng + dy - 1;
    if ((unsigned)w2 < 64u) {
      const uint8_t* xrow = xsl + (size_t)w2 * ROW_STRIDE;
      #pragma unroll
      for (int s = 0; s < 4; ++s) {
        const uint16_t* wp = wkv + ((size_t)(tap * 8 + s * 2 + lh) * 128 + lm) * 8;
        bf16x8 aK0 = *(const bf16x8*)(wp);
        bf16x8 aK1 = *(const bf16x8*)(wp + 32 * 8);
        bf16x8 aV0 = *(const bf16x8*)(wp + 64 * 8);
        bf16x8 aV1 = *(const bf16x8*)(wp + 96 * 8);
        bf16x8 b0 = *(const bf16x8*)(xrow + s * S_STRIDE + (lm + dx) * 32 + lh * 16);
        bf16x8 b1 = *(const bf16x8*)(xrow + s * S_STRIDE + (32 + lm + dx) * 32 + lh * 16);
        accK[0][0] = MFMA32(aK0, b0, accK[0][0]);
        accK[0][1] = MFMA32(aK0, b1, accK[0][1]);
        accK[1][0] = MFMA32(aK1, b0, accK[1][0]);
        accK[1][1] = MFMA32(aK1, b1, accK[1][1]);
        accV[0][0] = MFMA32(aV0, b0, accV[0][0]);
        accV[0][1] = MFMA32(aV0, b1, accV[0][1]);
        accV[1][0] = MFMA32(aV1, b0, accV[1][0]);
        accV[1][1] = MFMA32(aV1, b1, accV[1][1]);
      }
    }
  }

  float* sb = s_out + (b * 16 + t) * 64;
  #pragma unroll
  for (int q = 0; q < 16; ++q) {
    int cl = (q & 3) + 8 * (q >> 2) + 4 * lh;
    #pragma unroll
    for (int mt = 0; mt < 2; ++mt) {
      int c = mt * 32 + cl;
      float bkc = bk[c], bvc = bv[c];
      float p = (accK[mt][0][q] + bkc) * (accV[mt][0][q] + bvc)
              + (accK[mt][1][q] + bkc) * (accV[mt][1][q] + bvc);
      #pragma unroll
      for (int m = 1; m < 32; m <<= 1) p += __shfl_xor(p, m, 64);
      if (lm == 0) atomicAdd(sb + c, p);
    }
  }
}

// ---------------------------------------------------------------------------
// Q: zero LDS, zero barriers; fused epilogue, residual from xT (bf16).
// ---------------------------------------------------------------------------
__global__ __launch_bounds__(256, 3) void q_out_kernel(
    const uint8_t* __restrict__ xT, const uint16_t* __restrict__ wq,
    const float* __restrict__ bq, const float* __restrict__ s_in,
    const float* __restrict__ gamma, float* __restrict__ out) {
  const int tid = threadIdx.x;
  const int l = tid & 63, ng = tid >> 6;
  int bid = (int)(blockIdx.x & 7) * 256 + (int)(blockIdx.x >> 3);  // XCD swizzle
  const int rg = bid & 15, slice = bid >> 4;
  const int b = slice >> 4, t = slice & 15;
  const int w0 = rg * 4;
  const int lm = l & 31, lh = l >> 5;
  const uint8_t* xsl = xT + (size_t)slice * SLICE_STRIDE;

  f32x16 acc[2][2];
  #pragma unroll
  for (int mt = 0; mt < 2; ++mt)
    #pragma unroll
    for (int nt = 0; nt < 2; ++nt)
      #pragma unroll
      for (int q = 0; q < 16; ++q) acc[mt][nt][q] = 0.f;

  #pragma unroll
  for (int tap = 0; tap < 9; ++tap) {
    const int dy = tap / 3, dx = tap % 3;
    const int w2 = w0 + ng + dy - 1;
    if ((unsigned)w2 < 64u) {
      const uint8_t* xrow = xsl + (size_t)w2 * ROW_STRIDE;
      #pragma unroll
      for (int s = 0; s < 4; ++s) {
        const uint16_t* wp = wq + ((size_t)(tap * 8 + s * 2 + lh) * 64 + lm) * 8;
        bf16x8 a0 = *(const bf16x8*)(wp);
        bf16x8 a1 = *(const bf16x8*)(wp + 32 * 8);
        bf16x8 b0 = *(const bf16x8*)(xrow + s * S_STRIDE + (lm + dx) * 32 + lh * 16);
        bf16x8 b1 = *(const bf16x8*)(xrow + s * S_STRIDE + (32 + lm + dx) * 32 + lh * 16);
        acc[0][0] = MFMA32(a0, b0, acc[0][0]);
        acc[0][1] = MFMA32(a0, b1, acc[0][1]);
        acc[1][0] = MFMA32(a1, b0, acc[1][0]);
        acc[1][1] = MFMA32(a1, b1, acc[1][1]);
      }
    }
  }

  float g = gamma[0];
  const float* sb = s_in + (b * 16 + t) * 64;
  const int w = w0 + ng;
  const uint8_t* xrow = xsl + (size_t)w * ROW_STRIDE;
  #pragma unroll
  for (int mt = 0; mt < 2; ++mt) {
    #pragma unroll
    for (int q = 0; q < 16; ++q) {
      int cl = (q & 3) + 8 * (q >> 2) + 4 * lh;
      int c  = mt * 32 + cl;
      float qb = bq[c], sc = sb[c];
      #pragma unroll
      for (int nt = 0; nt < 2; ++nt) {
        int h = nt * 32 + lm;
        float xv = bf2f(*(const uint16_t*)(xrow + (c >> 4) * S_STRIDE + (h + 1) * 32
                                           + ((c >> 3) & 1) * 16 + (c & 7) * 2));
        size_t idx = ((size_t)(b * 64 + c) * 16 + t) * 4096 + (size_t)w * 64 + h;
        out[idx] = g * (acc[mt][nt][q] + qb) * sc + xv;
      }
    }
  }
}

extern "C" void kernel_launch(void* const* d_in, const int* in_sizes, int n_in,
                              void* d_out, int out_size, void* d_ws, size_t ws_size,
                              hipStream_t stream) {
  const float* x   = (const float*)d_in[0];
  const float* wq  = (const float*)d_in[1];
  const float* wk  = (const float*)d_in[2];
  const float* wv  = (const float*)d_in[3];
  const float* bq  = (const float*)d_in[4];
  const float* bk  = (const float*)d_in[5];
  const float* bv  = (const float*)d_in[6];
  const float* gam = (const float*)d_in[7];

  uint16_t* wbf = (uint16_t*)d_ws;                            // 221184 B
  float* sbuf   = (float*)((uint8_t*)d_ws + 221184);          // 32768 B
  uint8_t* xT   = (uint8_t*)d_ws + 262144;                    // 69206016 B
  if (ws_size < (size_t)262144 + 128 * (size_t)SLICE_STRIDE) return;  // fail loudly

  hipMemsetAsync(sbuf, 0, 8 * 16 * 64 * sizeof(float), stream);
  prep_weights<<<(110592 + 255) / 256, 256, 0, stream>>>(wq, wk, wv, wbf);
  transpose_x<<<2048, 256, 0, stream>>>(x, xT);
  kv_s_kernel<<<2048, 256, 0, stream>>>(xT, wbf + 36864, bk, bv, sbuf);
  q_out_kernel<<<2048, 256, 0, stream>>>(xT, wbf, bq, sbuf, gam, (float*)d_out);
}